// Round 1
// baseline (1009.460 us; speedup 1.0000x reference)
//
#include <hip/hip_runtime.h>
#include <cstdint>

#define TDIM 517
#define FEATD 120
#define NBB 16
#define NHEAD 24
#define NDIM 128
#define NKC 3072   // NHEAD*NDIM
#define LN_EPS 1e-5f

// ---------------------------------------------------------------------------
// K1: projection GEMM.  M = NBB*tc rows of X (rows are (bb,tt) pairs),
// 3*3072 output channels, K = 120.  Tile 64x64, f vectorized as float4.
// ---------------------------------------------------------------------------
__global__ __launch_bounds__(256) void proj_kernel(
    const float* __restrict__ x,
    const float* __restrict__ Wq, const float* __restrict__ Wk, const float* __restrict__ Wv,
    const float* __restrict__ bq, const float* __restrict__ bk, const float* __restrict__ bv,
    float* __restrict__ qb, float* __restrict__ kb, float* __restrict__ vb,
    int t0, int tc)
{
  // xs: [64 rows][124 floats] (31 float4 stride); wsl: [64 cols][124 floats]
  __shared__ float4 sm4[64 * 31 * 2];
  float* xs  = (float*)sm4;
  float* wsl = (float*)(sm4 + 64 * 31);
  const int tid   = threadIdx.x;
  const int Mrows = NBB * tc;
  const int m0    = blockIdx.x * 64;
  const int ct    = blockIdx.y;          // 0..143
  const int mat   = ct / 48;             // 0=q 1=k 2=v
  const int cbase = (ct % 48) * 64;
  const float* W    = (mat == 0) ? Wq : (mat == 1) ? Wk : Wv;
  const float* bias = (mat == 0) ? bq : (mat == 1) ? bk : bv;
  float* outb       = (mat == 0) ? qb : (mat == 1) ? kb : vb;

  // load X tile: f = idx/64 so consecutive tid -> consecutive t (coalesced)
  for (int idx = tid; idx < 64 * FEATD; idx += 256) {
    int f = idx / 64, rr = idx % 64;
    int row = m0 + rr;
    float v = 0.f;
    if (row < Mrows) {
      int bb = row / tc, tt = row % tc;
      v = x[((size_t)bb * FEATD + f) * TDIM + (t0 + tt)];
    }
    xs[rr * 124 + f] = v;
  }
  // load W tile (coalesced over f)
  for (int idx = tid; idx < 64 * FEATD; idx += 256) {
    int cc = idx / FEATD, f = idx % FEATD;
    wsl[cc * 124 + f] = W[(size_t)(cbase + cc) * FEATD + f];
  }
  __syncthreads();

  const int rl = tid & 15;    // row lane: rows rl+16i
  const int cg = tid >> 4;    // col group: cols cg+16j
  float acc[4][4] = {};
  const float4* xs4 = (const float4*)xs;
  const float4* ws4 = (const float4*)wsl;
  for (int f4 = 0; f4 < 30; ++f4) {
    float4 a[4], b[4];
#pragma unroll
    for (int i = 0; i < 4; ++i) a[i] = xs4[(rl + 16 * i) * 31 + f4];
#pragma unroll
    for (int j = 0; j < 4; ++j) b[j] = ws4[(cg + 16 * j) * 31 + f4];
#pragma unroll
    for (int i = 0; i < 4; ++i)
#pragma unroll
      for (int j = 0; j < 4; ++j) {
        acc[i][j] += a[i].x * b[j].x;
        acc[i][j] += a[i].y * b[j].y;
        acc[i][j] += a[i].z * b[j].z;
        acc[i][j] += a[i].w * b[j].w;
      }
  }

  // stage through LDS for coalesced global writes
  __syncthreads();
  float* st = xs;   // 64*65 floats fits in xs region
#pragma unroll
  for (int i = 0; i < 4; ++i)
#pragma unroll
    for (int j = 0; j < 4; ++j)
      st[(rl + 16 * i) * 65 + (cg + 16 * j)] = acc[i][j];
  __syncthreads();
  for (int idx = tid; idx < 4096; idx += 256) {
    int rr = idx >> 6, c = idx & 63;
    int row = m0 + rr;
    if (row < Mrows)
      outb[(size_t)row * NKC + cbase + c] = st[rr * 65 + c] + bias[cbase + c];
  }
}

// ---------------------------------------------------------------------------
// K2: per-(bb,t) attention over 24 heads of width 128.
// q,k staged transposed in LDS (stride 25 -> conflict-free), v plain.
// Output written back over q's slot (coalesced).
// ---------------------------------------------------------------------------
__global__ __launch_bounds__(256) void attn_kernel(
    float* __restrict__ qb, const float* __restrict__ kb, const float* __restrict__ vb)
{
  __shared__ float qs_t[NDIM * 25];   // [n][kk]
  __shared__ float ks_t[NDIM * 25];   // [n][m]
  __shared__ float vs[NHEAD * NDIM];  // [m][n]
  __shared__ float S[NHEAD * 25];     // scores then weights

  const int tid = threadIdx.x;
  const size_t base = (size_t)blockIdx.x * NKC;

  for (int i = tid; i < NKC; i += 256) {
    int kk = i >> 7, n = i & 127;
    qs_t[n * 25 + kk] = qb[base + i];
    ks_t[n * 25 + kk] = kb[base + i];
    vs[i] = vb[base + i];
  }
  __syncthreads();

  // scores S[kk][m] = sum_n q[kk][n]*k[m][n]
  for (int e = tid; e < NHEAD * NHEAD; e += 256) {
    int kk = e / NHEAD, m = e % NHEAD;
    float s = 0.f;
    for (int n = 0; n < NDIM; ++n)
      s += qs_t[n * 25 + kk] * ks_t[n * 25 + m];
    S[kk * 25 + m] = s;
  }
  __syncthreads();

  // softmax over m (one thread per row, tiny)
  if (tid < NHEAD) {
    float mx = -1e30f;
    for (int m = 0; m < NHEAD; ++m) mx = fmaxf(mx, S[tid * 25 + m]);
    float sum = 0.f;
    for (int m = 0; m < NHEAD; ++m) {
      float e = expf(S[tid * 25 + m] - mx);
      S[tid * 25 + m] = e;
      sum += e;
    }
    float inv = 1.f / sum;
    for (int m = 0; m < NHEAD; ++m) S[tid * 25 + m] *= inv;
  }
  __syncthreads();

  // out[kk][n] = sum_m wei[kk][m] * v[m][n]   (write over q slot)
  for (int c = tid; c < NKC; c += 256) {
    int kk = c >> 7, n = c & 127;
    float o = 0.f;
#pragma unroll 4
    for (int m = 0; m < NHEAD; ++m)
      o += S[kk * 25 + m] * vs[m * NDIM + n];
    qb[base + c] = o;
  }
}

// ---------------------------------------------------------------------------
// K3: transpose att [row=(bb,tt)][kk*128+n] -> pre-norm d_out [bb][n][kk][t]
// ---------------------------------------------------------------------------
__global__ __launch_bounds__(256) void transpose_kernel(
    const float* __restrict__ att, float* __restrict__ out, int t0, int tc)
{
  __shared__ float tile[32][129];
  const int tid = threadIdx.x;
  const int bb = blockIdx.z, kk = blockIdx.y;
  const int tt0 = blockIdx.x * 32;
  const int nt = min(32, tc - tt0);

  for (int idx = tid; idx < 32 * 128; idx += 256) {
    int n = idx & 127, ttl = idx >> 7;
    if (ttl < nt)
      tile[ttl][n] = att[((size_t)(bb * tc + tt0 + ttl)) * NKC + kk * NDIM + n];
  }
  __syncthreads();
  for (int idx = tid; idx < 32 * 128; idx += 256) {
    int ttl = idx & 31, n = idx >> 5;
    if (ttl < nt)
      out[(((size_t)bb * NDIM + n) * NHEAD + kk) * TDIM + (t0 + tt0 + ttl)] = tile[ttl][n];
  }
}

// ---------------------------------------------------------------------------
// K4: LayerNorm stats per (bb,kk) over (n,t): 128*517 elems
// ---------------------------------------------------------------------------
__global__ __launch_bounds__(256) void ln_stats_kernel(
    const float* __restrict__ out, float* __restrict__ stats)
{
  const int b = blockIdx.x;            // bb*24+kk
  const int bb = b / NHEAD, kk = b % NHEAD;
  const int tid = threadIdx.x;
  float s = 0.f, s2 = 0.f;
  for (int idx = tid; idx < NDIM * TDIM; idx += 256) {
    int n = idx / TDIM, t = idx % TDIM;
    float v = out[(((size_t)bb * NDIM + n) * NHEAD + kk) * TDIM + t];
    s += v; s2 += v * v;
  }
  __shared__ float rs[256], rs2[256];
  rs[tid] = s; rs2[tid] = s2;
  __syncthreads();
  for (int off = 128; off > 0; off >>= 1) {
    if (tid < off) { rs[tid] += rs[tid + off]; rs2[tid] += rs2[tid + off]; }
    __syncthreads();
  }
  if (tid == 0) {
    const float inv = 1.f / (NDIM * TDIM);
    float mu = rs[0] * inv;
    float var = rs2[0] * inv - mu * mu;
    stats[b] = mu;
    stats[384 + b] = rsqrtf(var + LN_EPS);
  }
}

// ---------------------------------------------------------------------------
// K5: in-place normalize + gamma/beta
// ---------------------------------------------------------------------------
__global__ __launch_bounds__(256) void ln_apply_kernel(
    float* __restrict__ out, const float* __restrict__ stats,
    const float* __restrict__ gamma, const float* __restrict__ beta)
{
  const size_t total = (size_t)NBB * NDIM * NHEAD * TDIM;
  for (size_t idx = (size_t)blockIdx.x * blockDim.x + threadIdx.x; idx < total;
       idx += (size_t)gridDim.x * blockDim.x) {
    int t = (int)(idx % TDIM);
    size_t r = idx / TDIM;
    int kk = (int)(r % NHEAD); r /= NHEAD;
    int n = (int)(r % NDIM);
    int bb = (int)(r / NDIM);
    float mu = stats[bb * NHEAD + kk];
    float rstd = stats[384 + bb * NHEAD + kk];
    float v = out[idx];
    out[idx] = (v - mu) * rstd * gamma[n * TDIM + t] + beta[n * TDIM + t];
  }
}

// ---------------------------------------------------------------------------
extern "C" void kernel_launch(void* const* d_in, const int* in_sizes, int n_in,
                              void* d_out, int out_size, void* d_ws, size_t ws_size,
                              hipStream_t stream) {
  const float* x     = (const float*)d_in[0];
  const float* Wq    = (const float*)d_in[1];
  const float* bq    = (const float*)d_in[2];
  const float* Wk    = (const float*)d_in[3];
  const float* bk    = (const float*)d_in[4];
  const float* Wv    = (const float*)d_in[5];
  const float* bv    = (const float*)d_in[6];
  const float* gamma = (const float*)d_in[7];
  const float* beta  = (const float*)d_in[8];
  float* out = (float*)d_out;
  float* ws  = (float*)d_ws;

  const size_t statsF = 1024;                      // stats area (mu[384], rstd[384])
  const size_t perT   = (size_t)NBB * 3 * NKC;     // floats of qkv per t = 147456
  size_t availF = ws_size / sizeof(float);
  int Tc = 1;
  if (availF > statsF) {
    size_t tcap = (availF - statsF) / perT;
    Tc = (tcap >= TDIM) ? TDIM : (int)tcap;
    if (Tc < 1) Tc = 1;
  }

  float* qb = ws + statsF;
  float* kb = qb + (size_t)NBB * Tc * NKC;
  float* vb = kb + (size_t)NBB * Tc * NKC;

  for (int t0 = 0; t0 < TDIM; t0 += Tc) {
    int tc = (TDIM - t0 < Tc) ? (TDIM - t0) : Tc;
    dim3 g1((NBB * tc + 63) / 64, 144);
    proj_kernel<<<g1, 256, 0, stream>>>(x, Wq, Wk, Wv, bq, bk, bv, qb, kb, vb, t0, tc);
    attn_kernel<<<NBB * tc, 256, 0, stream>>>(qb, kb, vb);
    dim3 g3((tc + 31) / 32, NHEAD, NBB);
    transpose_kernel<<<g3, 256, 0, stream>>>(qb, out, t0, tc);
  }
  ln_stats_kernel<<<NBB * NHEAD, 256, 0, stream>>>(out, ws);
  ln_apply_kernel<<<4096, 256, 0, stream>>>(out, ws, gamma, beta);
}

// Round 2
// 262.812 us; speedup vs baseline: 3.8410x; 3.8410x over previous
//
#include <hip/hip_runtime.h>
#include <hip/hip_bf16.h>
#include <cstdint>

#define TDIM 517
#define FEATD 120
#define NBB 16
#define NHEAD 24
#define NDIM 128
#define NKC 3072            // NHEAD*NDIM
#define MROWS (NBB * TDIM)  // 8272
#define MPAD 8320           // 65 * 128
#define NCOLS (3 * NKC)     // 9216
#define KPAD 128
#define LN_EPS 1e-5f

typedef short bf16x8 __attribute__((ext_vector_type(8)));
typedef float f32x4 __attribute__((ext_vector_type(4)));

static __device__ __forceinline__ float bf2f(ushort u) {
  union { uint i; float f; } v; v.i = ((uint)u) << 16; return v.f;
}
static __device__ __forceinline__ ushort f2bf(float f) {
  __hip_bfloat16 h = __float2bfloat16(f);   // RNE
  return *reinterpret_cast<ushort*>(&h);
}

// ---------------------------------------------------------------------------
// K0a: x [16][120][517] f32  ->  A [row=(bb*517+tt)][kpad=128] bf16 (f>=120 zero)
// ---------------------------------------------------------------------------
__global__ __launch_bounds__(256) void convert_x_kernel(
    const float* __restrict__ x, ushort* __restrict__ A)
{
  __shared__ float tile[FEATD][65];
  const int tid = threadIdx.x;
  const int bb = blockIdx.y;
  const int t0 = blockIdx.x * 64;
  const int nt = min(64, TDIM - t0);
  for (int idx = tid; idx < FEATD * 64; idx += 256) {
    int f = idx >> 6, tl = idx & 63;
    if (tl < nt) tile[f][tl] = x[((size_t)bb * FEATD + f) * TDIM + t0 + tl];
  }
  __syncthreads();
  for (int c = tid; c < 64 * 16; c += 256) {
    int tl = c >> 4, c8 = c & 15;
    if (tl >= nt) continue;
    ushort u[8];
    if (c8 < 15) {
#pragma unroll
      for (int j = 0; j < 8; ++j) u[j] = f2bf(tile[c8 * 8 + j][tl]);
    } else {
#pragma unroll
      for (int j = 0; j < 8; ++j) u[j] = 0;
    }
    size_t row = (size_t)bb * TDIM + t0 + tl;
    *reinterpret_cast<uint4*>(A + row * KPAD + c8 * 8) = *reinterpret_cast<const uint4*>(u);
  }
}

// ---------------------------------------------------------------------------
// K0b: W{q,k,v} [3072][120] f32 -> B [9216][128] bf16; also zero A tail rows
// ---------------------------------------------------------------------------
__global__ __launch_bounds__(256) void convert_w_kernel(
    const float* __restrict__ Wq, const float* __restrict__ Wk, const float* __restrict__ Wv,
    ushort* __restrict__ B, ushort* __restrict__ A)
{
  const int c = blockIdx.x * 256 + threadIdx.x;
  if (c < NCOLS * 16) {
    int col = c >> 4, c8 = c & 15;
    ushort u[8];
    if (c8 < 15) {
      const float* W = (col < NKC)     ? (Wq + (size_t)col * FEATD)
                     : (col < 2 * NKC) ? (Wk + (size_t)(col - NKC) * FEATD)
                                       : (Wv + (size_t)(col - 2 * NKC) * FEATD);
#pragma unroll
      for (int j = 0; j < 8; ++j) u[j] = f2bf(W[c8 * 8 + j]);
    } else {
#pragma unroll
      for (int j = 0; j < 8; ++j) u[j] = 0;
    }
    *reinterpret_cast<uint4*>(B + (size_t)col * KPAD + c8 * 8) = *reinterpret_cast<const uint4*>(u);
  }
  if (c < (MPAD - MROWS) * 16) {
    uint4 z = {0, 0, 0, 0};
    *reinterpret_cast<uint4*>(A + (size_t)(MROWS + (c >> 4)) * KPAD + (c & 15) * 8) = z;
  }
}

// ---------------------------------------------------------------------------
// K1: MFMA projection GEMM.  C[M=8272][N=9216] = A[M][128] * B[N][128]^T + bias
// 128x128 tile, 4 waves (2x2), single K pass (4 x k32), XOR-swizzled LDS.
// Output bf16 into q/k/v (per 24-block column groups).
// ---------------------------------------------------------------------------
__global__ __launch_bounds__(256) void proj_mfma_kernel(
    const ushort* __restrict__ A, const ushort* __restrict__ B,
    const float* __restrict__ bq, const float* __restrict__ bk, const float* __restrict__ bv,
    ushort* __restrict__ qb, ushort* __restrict__ kb, ushort* __restrict__ vb)
{
  __shared__ __align__(16) ushort sA[128 * KPAD];
  __shared__ __align__(16) ushort sB[128 * KPAD];
  __shared__ float sBias[128];
  const int tid  = threadIdx.x;
  const int lane = tid & 63;
  const int wave = tid >> 6;
  const int wm0  = (wave >> 1) * 64;
  const int wn0  = (wave & 1) * 64;
  const int m0   = blockIdx.x * 128;
  const int n0   = blockIdx.y * 128;
  const int mat  = blockIdx.y / 24;      // 24 column-blocks per matrix
  const int nloc0 = n0 - mat * NKC;
  const float* bias = (mat == 0) ? bq : (mat == 1) ? bk : bv;
  ushort* outb      = (mat == 0) ? qb : (mat == 1) ? kb : vb;

  if (tid < 128) sBias[tid] = bias[nloc0 + tid];

#pragma unroll
  for (int i = 0; i < 8; ++i) {
    int c = tid + i * 256;
    int row = c >> 4, c8 = c & 15;
    uint4 va = *reinterpret_cast<const uint4*>(A + (size_t)(m0 + row) * KPAD + c8 * 8);
    uint4 vb4 = *reinterpret_cast<const uint4*>(B + (size_t)(n0 + row) * KPAD + c8 * 8);
    *reinterpret_cast<uint4*>(&sA[row * KPAD + ((c8 ^ (row & 7)) << 3)]) = va;
    *reinterpret_cast<uint4*>(&sB[row * KPAD + ((c8 ^ (row & 7)) << 3)]) = vb4;
  }
  __syncthreads();

  f32x4 acc[4][4];
#pragma unroll
  for (int i = 0; i < 4; ++i)
#pragma unroll
    for (int j = 0; j < 4; ++j) acc[i][j] = (f32x4){0.f, 0.f, 0.f, 0.f};

  const int rl = lane & 15;
  const int kg = lane >> 4;
#pragma unroll
  for (int s = 0; s < 4; ++s) {
    bf16x8 af[4], bfr[4];
    const int c8 = s * 4 + kg;
#pragma unroll
    for (int i = 0; i < 4; ++i) {
      int row = wm0 + i * 16 + rl;
      af[i] = *reinterpret_cast<const bf16x8*>(&sA[row * KPAD + ((c8 ^ (row & 7)) << 3)]);
      int rowb = wn0 + i * 16 + rl;
      bfr[i] = *reinterpret_cast<const bf16x8*>(&sB[rowb * KPAD + ((c8 ^ (rowb & 7)) << 3)]);
    }
#pragma unroll
    for (int i = 0; i < 4; ++i)
#pragma unroll
      for (int j = 0; j < 4; ++j)
        acc[i][j] = __builtin_amdgcn_mfma_f32_16x16x32_bf16(af[i], bfr[j], acc[i][j], 0, 0, 0);
  }

  __syncthreads();
  // acc -> bf16 C tile in LDS (reuse sA), bias fused
  ushort* sC = sA;
#pragma unroll
  for (int i = 0; i < 4; ++i)
#pragma unroll
    for (int j = 0; j < 4; ++j) {
      int col = wn0 + j * 16 + rl;
      float bsv = sBias[col];
#pragma unroll
      for (int r = 0; r < 4; ++r) {
        int row = wm0 + i * 16 + kg * 4 + r;
        sC[row * 128 + col] = f2bf(acc[i][j][r] + bsv);
      }
    }
  __syncthreads();
#pragma unroll
  for (int i = 0; i < 8; ++i) {
    int c = tid + i * 256;
    int row = c >> 4, c8 = c & 15;
    int grow = m0 + row;
    if (grow < MROWS)
      *reinterpret_cast<uint4*>(outb + (size_t)grow * NKC + nloc0 + c8 * 8) =
          *reinterpret_cast<const uint4*>(&sC[row * 128 + c8 * 8]);
  }
}

// ---------------------------------------------------------------------------
// K2: per-(bb,t) attention over 24 heads of width 128 (bf16 in/out, f32 math)
// ---------------------------------------------------------------------------
__global__ __launch_bounds__(256) void attn_kernel(
    ushort* __restrict__ qb, const ushort* __restrict__ kb, const ushort* __restrict__ vb)
{
  __shared__ float qs_t[NDIM * 25];   // [n][kk]
  __shared__ float ks_t[NDIM * 25];   // [n][m]
  __shared__ float vs[NHEAD * NDIM];  // [m][n]
  __shared__ float S[NHEAD * 25];
  const int tid = threadIdx.x;
  const size_t base = (size_t)blockIdx.x * NKC;

  // stage as 2-element chunks: conflict-light transposed scatter
  for (int c = tid; c < NKC / 2; c += 256) {
    int kk = c >> 6, n0 = (c & 63) * 2;
    uint vq = *reinterpret_cast<const uint*>(qb + base + kk * NDIM + n0);
    uint vk = *reinterpret_cast<const uint*>(kb + base + kk * NDIM + n0);
    uint vv = *reinterpret_cast<const uint*>(vb + base + kk * NDIM + n0);
#pragma unroll
    for (int j = 0; j < 2; ++j) {
      qs_t[(n0 + j) * 25 + kk] = bf2f((ushort)((vq >> (16 * j)) & 0xffff));
      ks_t[(n0 + j) * 25 + kk] = bf2f((ushort)((vk >> (16 * j)) & 0xffff));
      vs[kk * NDIM + n0 + j]   = bf2f((ushort)((vv >> (16 * j)) & 0xffff));
    }
  }
  __syncthreads();

  for (int e = tid; e < NHEAD * NHEAD; e += 256) {
    int kk = e / NHEAD, m = e % NHEAD;
    float s = 0.f;
#pragma unroll 4
    for (int n = 0; n < NDIM; ++n)
      s += qs_t[n * 25 + kk] * ks_t[n * 25 + m];
    S[kk * 25 + m] = s;
  }
  __syncthreads();

  if (tid < NHEAD) {
    float mx = -1e30f;
    for (int m = 0; m < NHEAD; ++m) mx = fmaxf(mx, S[tid * 25 + m]);
    float sum = 0.f;
    for (int m = 0; m < NHEAD; ++m) {
      float e = expf(S[tid * 25 + m] - mx);
      S[tid * 25 + m] = e;
      sum += e;
    }
    float inv = 1.f / sum;
    for (int m = 0; m < NHEAD; ++m) S[tid * 25 + m] *= inv;
  }
  __syncthreads();

  for (int c = tid; c < NKC / 2; c += 256) {
    int kk = c >> 6, n0 = (c & 63) * 2;
    float o0 = 0.f, o1 = 0.f;
#pragma unroll 4
    for (int m = 0; m < NHEAD; ++m) {
      float w = S[kk * 25 + m];
      o0 += w * vs[m * NDIM + n0];
      o1 += w * vs[m * NDIM + n0 + 1];
    }
    uint packed = (uint)f2bf(o0) | ((uint)f2bf(o1) << 16);
    *reinterpret_cast<uint*>(qb + base + kk * NDIM + n0) = packed;
  }
}

// ---------------------------------------------------------------------------
// K3: LN stats per (bb,kk) directly from att layout [row=(bb,t)][kk*128+n]
// ---------------------------------------------------------------------------
__global__ __launch_bounds__(256) void ln_stats_kernel(
    const ushort* __restrict__ att, float* __restrict__ stats)
{
  const int b = blockIdx.x;  // bb*24+kk
  const int bb = b / NHEAD, kk = b % NHEAD;
  const int tid = threadIdx.x;
  float s = 0.f, s2 = 0.f;
  for (int c = tid; c < TDIM * 16; c += 256) {
    int tt = c >> 4, n0 = (c & 15) * 8;
    uint4 v = *reinterpret_cast<const uint4*>(
        att + ((size_t)(bb * TDIM + tt)) * NKC + kk * NDIM + n0);
    const ushort* u = reinterpret_cast<const ushort*>(&v);
#pragma unroll
    for (int j = 0; j < 8; ++j) { float f = bf2f(u[j]); s += f; s2 += f * f; }
  }
  __shared__ float rs[256], rs2[256];
  rs[tid] = s; rs2[tid] = s2;
  __syncthreads();
  for (int off = 128; off > 0; off >>= 1) {
    if (tid < off) { rs[tid] += rs[tid + off]; rs2[tid] += rs2[tid + off]; }
    __syncthreads();
  }
  if (tid == 0) {
    const float inv = 1.f / (NDIM * TDIM);
    float mu = rs[0] * inv;
    float var = rs2[0] * inv - mu * mu;
    stats[b] = mu;
    stats[384 + b] = rsqrtf(var + LN_EPS);
  }
}

// ---------------------------------------------------------------------------
// K4: fused transpose + LN apply: att bf16 -> out f32 [bb][n][kk][t]
// ---------------------------------------------------------------------------
__global__ __launch_bounds__(256) void transpose_apply_kernel(
    const ushort* __restrict__ att, const float* __restrict__ stats,
    const float* __restrict__ gamma, const float* __restrict__ beta,
    float* __restrict__ out)
{
  __shared__ float tile[32][NDIM + 1];
  const int tid = threadIdx.x;
  const int bb = blockIdx.z, kk = blockIdx.y;
  const int t0 = blockIdx.x * 32;
  const float mu = stats[bb * NHEAD + kk];
  const float rstd = stats[384 + bb * NHEAD + kk];

  for (int c = tid; c < 32 * 16; c += 256) {
    int tl = c >> 4, n0 = (c & 15) * 8;
    if (t0 + tl < TDIM) {
      uint4 v = *reinterpret_cast<const uint4*>(
          att + ((size_t)(bb * TDIM + t0 + tl)) * NKC + kk * NDIM + n0);
      const ushort* u = reinterpret_cast<const ushort*>(&v);
#pragma unroll
      for (int j = 0; j < 8; ++j) tile[tl][n0 + j] = bf2f(u[j]);
    }
  }
  __syncthreads();
  for (int c = tid; c < NDIM * 32; c += 256) {
    int n = c >> 5, tl = c & 31;
    int t = t0 + tl;
    if (t < TDIM) {
      float g  = gamma[(size_t)n * TDIM + t];
      float bt = beta[(size_t)n * TDIM + t];
      out[(((size_t)bb * NDIM + n) * NHEAD + kk) * TDIM + t] =
          (tile[tl][n] - mu) * rstd * g + bt;
    }
  }
}

// ---------------------------------------------------------------------------
extern "C" void kernel_launch(void* const* d_in, const int* in_sizes, int n_in,
                              void* d_out, int out_size, void* d_ws, size_t ws_size,
                              hipStream_t stream) {
  const float* x     = (const float*)d_in[0];
  const float* Wq    = (const float*)d_in[1];
  const float* bq    = (const float*)d_in[2];
  const float* Wk    = (const float*)d_in[3];
  const float* bk    = (const float*)d_in[4];
  const float* Wv    = (const float*)d_in[5];
  const float* bv    = (const float*)d_in[6];
  const float* gamma = (const float*)d_in[7];
  const float* beta  = (const float*)d_in[8];
  float* out = (float*)d_out;

  char* wsb = (char*)d_ws;
  float* stats = (float*)wsb;                       // 1024 floats
  ushort* A = (ushort*)(wsb + 4096);                // [8320][128]
  ushort* B = A + (size_t)MPAD * KPAD;              // [9216][128]
  ushort* qb = B + (size_t)NCOLS * KPAD;            // [8272][3072] each
  ushort* kb = qb + (size_t)MROWS * NKC;
  ushort* vb = kb + (size_t)MROWS * NKC;

  convert_x_kernel<<<dim3(9, NBB), 256, 0, stream>>>(x, A);
  convert_w_kernel<<<(NCOLS * 16 + 255) / 256, 256, 0, stream>>>(Wq, Wk, Wv, B, A);
  proj_mfma_kernel<<<dim3(MPAD / 128, NCOLS / 128), 256, 0, stream>>>(
      A, B, bq, bk, bv, qb, kb, vb);
  attn_kernel<<<MROWS, 256, 0, stream>>>(qb, kb, vb);
  ln_stats_kernel<<<NBB * NHEAD, 256, 0, stream>>>(qb, stats);
  transpose_apply_kernel<<<dim3((TDIM + 31) / 32, NHEAD, NBB), 256, 0, stream>>>(
      qb, stats, gamma, beta, out);
}

// Round 5
// 217.128 us; speedup vs baseline: 4.6491x; 1.2104x over previous
//
#include <hip/hip_runtime.h>
#include <hip/hip_bf16.h>
#include <cstdint>

#define TDIM 517
#define FEATD 120
#define NBB 16
#define NHEAD 24
#define NDIM 128
#define NKC 3072            // NHEAD*NDIM
#define MROWS (NBB * TDIM)  // 8272
#define MPAD 8320           // 65 * 128
#define NCOLS (3 * NKC)     // 9216
#define KPAD 128
#define LN_EPS 1e-5f

typedef short bf16x8 __attribute__((ext_vector_type(8)));
typedef short bf16x4 __attribute__((ext_vector_type(4)));
typedef float f32x4 __attribute__((ext_vector_type(4)));

static __device__ __forceinline__ float bf2f(ushort u) {
  union { uint i; float f; } v; v.i = ((uint)u) << 16; return v.f;
}
static __device__ __forceinline__ ushort f2bf(float f) {
  __hip_bfloat16 h = __float2bfloat16(f);   // RNE
  return *reinterpret_cast<ushort*>(&h);
}

// ---------------------------------------------------------------------------
// K0a: x [16][120][517] f32  ->  A [row=(bb*517+tt)][kpad=128] bf16 (f>=120 zero)
// ---------------------------------------------------------------------------
__global__ __launch_bounds__(256) void convert_x_kernel(
    const float* __restrict__ x, ushort* __restrict__ A)
{
  __shared__ float tile[FEATD][65];
  const int tid = threadIdx.x;
  const int bb = blockIdx.y;
  const int t0 = blockIdx.x * 64;
  const int nt = min(64, TDIM - t0);
  for (int idx = tid; idx < FEATD * 64; idx += 256) {
    int f = idx >> 6, tl = idx & 63;
    if (tl < nt) tile[f][tl] = x[((size_t)bb * FEATD + f) * TDIM + t0 + tl];
  }
  __syncthreads();
  for (int c = tid; c < 64 * 16; c += 256) {
    int tl = c >> 4, c8 = c & 15;
    if (tl >= nt) continue;
    ushort u[8];
    if (c8 < 15) {
#pragma unroll
      for (int j = 0; j < 8; ++j) u[j] = f2bf(tile[c8 * 8 + j][tl]);
    } else {
#pragma unroll
      for (int j = 0; j < 8; ++j) u[j] = 0;
    }
    size_t row = (size_t)bb * TDIM + t0 + tl;
    *reinterpret_cast<uint4*>(A + row * KPAD + c8 * 8) = *reinterpret_cast<const uint4*>(u);
  }
}

// ---------------------------------------------------------------------------
// K0b: W{q,k,v} [3072][120] f32 -> B [9216][128] bf16; also zero A tail rows
// ---------------------------------------------------------------------------
__global__ __launch_bounds__(256) void convert_w_kernel(
    const float* __restrict__ Wq, const float* __restrict__ Wk, const float* __restrict__ Wv,
    ushort* __restrict__ B, ushort* __restrict__ A)
{
  const int c = blockIdx.x * 256 + threadIdx.x;
  if (c < NCOLS * 16) {
    int col = c >> 4, c8 = c & 15;
    ushort u[8];
    if (c8 < 15) {
      const float* W = (col < NKC)     ? (Wq + (size_t)col * FEATD)
                     : (col < 2 * NKC) ? (Wk + (size_t)(col - NKC) * FEATD)
                                       : (Wv + (size_t)(col - 2 * NKC) * FEATD);
#pragma unroll
      for (int j = 0; j < 8; ++j) u[j] = f2bf(W[c8 * 8 + j]);
    } else {
#pragma unroll
      for (int j = 0; j < 8; ++j) u[j] = 0;
    }
    *reinterpret_cast<uint4*>(B + (size_t)col * KPAD + c8 * 8) = *reinterpret_cast<const uint4*>(u);
  }
  if (c < (MPAD - MROWS) * 16) {
    uint4 z = {0, 0, 0, 0};
    *reinterpret_cast<uint4*>(A + (size_t)(MROWS + (c >> 4)) * KPAD + (c & 15) * 8) = z;
  }
}

// ---------------------------------------------------------------------------
// K1: MFMA projection GEMM (unchanged from R2)
// ---------------------------------------------------------------------------
__global__ __launch_bounds__(256) void proj_mfma_kernel(
    const ushort* __restrict__ A, const ushort* __restrict__ B,
    const float* __restrict__ bq, const float* __restrict__ bk, const float* __restrict__ bv,
    ushort* __restrict__ qb, ushort* __restrict__ kb, ushort* __restrict__ vb)
{
  __shared__ __align__(16) ushort sA[128 * KPAD];
  __shared__ __align__(16) ushort sB[128 * KPAD];
  __shared__ float sBias[128];
  const int tid  = threadIdx.x;
  const int lane = tid & 63;
  const int wave = tid >> 6;
  const int wm0  = (wave >> 1) * 64;
  const int wn0  = (wave & 1) * 64;
  const int m0   = blockIdx.x * 128;
  const int n0   = blockIdx.y * 128;
  const int mat  = blockIdx.y / 24;
  const int nloc0 = n0 - mat * NKC;
  const float* bias = (mat == 0) ? bq : (mat == 1) ? bk : bv;
  ushort* outb      = (mat == 0) ? qb : (mat == 1) ? kb : vb;

  if (tid < 128) sBias[tid] = bias[nloc0 + tid];

#pragma unroll
  for (int i = 0; i < 8; ++i) {
    int c = tid + i * 256;
    int row = c >> 4, c8 = c & 15;
    uint4 va = *reinterpret_cast<const uint4*>(A + (size_t)(m0 + row) * KPAD + c8 * 8);
    uint4 vb4 = *reinterpret_cast<const uint4*>(B + (size_t)(n0 + row) * KPAD + c8 * 8);
    *reinterpret_cast<uint4*>(&sA[row * KPAD + ((c8 ^ (row & 7)) << 3)]) = va;
    *reinterpret_cast<uint4*>(&sB[row * KPAD + ((c8 ^ (row & 7)) << 3)]) = vb4;
  }
  __syncthreads();

  f32x4 acc[4][4];
#pragma unroll
  for (int i = 0; i < 4; ++i)
#pragma unroll
    for (int j = 0; j < 4; ++j) acc[i][j] = (f32x4){0.f, 0.f, 0.f, 0.f};

  const int rl = lane & 15;
  const int kg = lane >> 4;
#pragma unroll
  for (int s = 0; s < 4; ++s) {
    bf16x8 af[4], bfr[4];
    const int c8 = s * 4 + kg;
#pragma unroll
    for (int i = 0; i < 4; ++i) {
      int row = wm0 + i * 16 + rl;
      af[i] = *reinterpret_cast<const bf16x8*>(&sA[row * KPAD + ((c8 ^ (row & 7)) << 3)]);
      int rowb = wn0 + i * 16 + rl;
      bfr[i] = *reinterpret_cast<const bf16x8*>(&sB[rowb * KPAD + ((c8 ^ (rowb & 7)) << 3)]);
    }
#pragma unroll
    for (int i = 0; i < 4; ++i)
#pragma unroll
      for (int j = 0; j < 4; ++j)
        acc[i][j] = __builtin_amdgcn_mfma_f32_16x16x32_bf16(af[i], bfr[j], acc[i][j], 0, 0, 0);
  }

  __syncthreads();
  ushort* sC = sA;
#pragma unroll
  for (int i = 0; i < 4; ++i)
#pragma unroll
    for (int j = 0; j < 4; ++j) {
      int col = wn0 + j * 16 + rl;
      float bsv = sBias[col];
#pragma unroll
      for (int r = 0; r < 4; ++r) {
        int row = wm0 + i * 16 + kg * 4 + r;
        sC[row * 128 + col] = f2bf(acc[i][j][r] + bsv);
      }
    }
  __syncthreads();
#pragma unroll
  for (int i = 0; i < 8; ++i) {
    int c = tid + i * 256;
    int row = c >> 4, c8 = c & 15;
    int grow = m0 + row;
    if (grow < MROWS)
      *reinterpret_cast<uint4*>(outb + (size_t)grow * NKC + nloc0 + c8 * 8) =
          *reinterpret_cast<const uint4*>(&sC[row * 128 + c8 * 8]);
  }
}

// ---------------------------------------------------------------------------
// K2: MFMA attention. 1 wave per (bb,t); 4 waves/block; per-wave LDS slices.
// QK^T/PV on 16x16x32 bf16 MFMA. V transposed into LDS (stride 36, padded)
// via scalar scatter; PV B-frags = two aligned b64 reads (no tr-read: R4's
// absmax-10 suspect was the ds_read_b64_tr_b16 semantics — this path is
// fully derivable and compiler-synchronized).
// Per-wave LDS (halfwords): vT 4608 ([n=128][36], m in 0..35), wei 32x36.
// ---------------------------------------------------------------------------
#define WAVE_LDS 5760
__global__ __launch_bounds__(256) void attn_mfma_kernel(
    const ushort* __restrict__ qb, const ushort* __restrict__ kb,
    const ushort* __restrict__ vb, float* __restrict__ obuf)
{
  __shared__ __align__(16) ushort lds[4 * WAVE_LDS];
  const int tid  = threadIdx.x;
  const int wave = tid >> 6;
  const int lane = tid & 63;
  const int c = lane & 15;
  const int g = lane >> 4;
  const int p = blockIdx.x * 4 + wave;
  ushort* vT = lds + wave * WAVE_LDS;   // [n][36]: vT[n*36+m] = V[m][n]
  ushort* wL = vT + 4608;               // [row][36]: wei
  const ushort* qp = qb + (size_t)p * NKC;
  const ushort* kp = kb + (size_t)p * NKC;
  const ushort* vp = vb + (size_t)p * NKC;

  // ---- issue V global loads early (T14: hide under QK^T+softmax) ----
  uint4 vload[6];
#pragma unroll
  for (int it = 0; it < 6; ++it) {
    int idx = it * 64 + lane;
    int m = idx >> 4, n0 = (idx & 15) * 8;
    vload[it] = *reinterpret_cast<const uint4*>(vp + m * 128 + n0);
  }

  // ---- QK^T: S[kk][m], kk rows on A(Q), m cols on B(K) ----
  f32x4 sc[2][2];
#pragma unroll
  for (int i = 0; i < 2; ++i)
#pragma unroll
    for (int j = 0; j < 2; ++j) sc[i][j] = (f32x4){0.f, 0.f, 0.f, 0.f};

#pragma unroll
  for (int s = 0; s < 4; ++s) {
    bf16x8 aq[2], bk2[2];
#pragma unroll
    for (int i = 0; i < 2; ++i)
      aq[i] = *reinterpret_cast<const bf16x8*>(qp + (i * 16 + c) * 128 + s * 32 + g * 8);
#pragma unroll
    for (int j = 0; j < 2; ++j)
      bk2[j] = *reinterpret_cast<const bf16x8*>(kp + (j * 16 + c) * 128 + s * 32 + g * 8);
#pragma unroll
    for (int i = 0; i < 2; ++i)
#pragma unroll
      for (int j = 0; j < 2; ++j)
        sc[i][j] = __builtin_amdgcn_mfma_f32_16x16x32_bf16(aq[i], bk2[j], sc[i][j], 0, 0, 0);
  }

  // ---- softmax over m per row; lane holds S[i*16+g*4+r][j*16+c] ----
  // mask m>=24: j==1 && c>=8. Write wei (bf16) to wL[row][m], stride 36 hw.
#pragma unroll
  for (int i = 0; i < 2; ++i) {
#pragma unroll
    for (int r = 0; r < 4; ++r) {
      float s0 = sc[i][0][r];
      float s1 = (c < 8) ? sc[i][1][r] : -1e30f;
      float mx = fmaxf(s0, s1);
#pragma unroll
      for (int d = 1; d < 16; d <<= 1) mx = fmaxf(mx, __shfl_xor(mx, d));
      float e0 = __expf(s0 - mx);
      float e1 = (c < 8) ? __expf(s1 - mx) : 0.f;
      float sum = e0 + e1;
#pragma unroll
      for (int d = 1; d < 16; d <<= 1) sum += __shfl_xor(sum, d);
      float inv = 1.f / sum;
      int row = i * 16 + g * 4 + r;
      wL[row * 36 + c]      = f2bf(e0 * inv);
      wL[row * 36 + 16 + c] = f2bf(e1 * inv);
    }
  }

  // ---- stage V transposed: vT[n*36 + m] = V[m][n] (scalar scatter) ----
#pragma unroll
  for (int it = 0; it < 6; ++it) {
    int idx = it * 64 + lane;
    int m = idx >> 4, n0 = (idx & 15) * 8;
    uint w0 = vload[it].x, w1 = vload[it].y, w2 = vload[it].z, w3 = vload[it].w;
    vT[(n0 + 0) * 36 + m] = (ushort)(w0 & 0xffff);
    vT[(n0 + 1) * 36 + m] = (ushort)(w0 >> 16);
    vT[(n0 + 2) * 36 + m] = (ushort)(w1 & 0xffff);
    vT[(n0 + 3) * 36 + m] = (ushort)(w1 >> 16);
    vT[(n0 + 4) * 36 + m] = (ushort)(w2 & 0xffff);
    vT[(n0 + 5) * 36 + m] = (ushort)(w2 >> 16);
    vT[(n0 + 6) * 36 + m] = (ushort)(w3 & 0xffff);
    vT[(n0 + 7) * 36 + m] = (ushort)(w3 >> 16);
  }
  // zero pad m=24..31 for all n (ALL halfwords — R3 lesson)
#pragma unroll
  for (int h = 0; h < 16; ++h) {
    int idx = h * 64 + lane;        // 0..1023
    int n = idx >> 3, mm = 24 + (idx & 7);
    vT[n * 36 + mm] = 0;
  }

  // ---- PV A-frags (wei): row=i*16+c, k-chunk g*8 ----
  union FU { bf16x4 h[2]; bf16x8 v; };
  bf16x8 wa[2];
#pragma unroll
  for (int i = 0; i < 2; ++i) {
    FU u;
    u.h[0] = *reinterpret_cast<const bf16x4*>(wL + (i * 16 + c) * 36 + g * 8);
    u.h[1] = *reinterpret_cast<const bf16x4*>(wL + (i * 16 + c) * 36 + g * 8 + 4);
    wa[i] = u.v;
  }

  // ---- PV: B-frag lane (c,g) = V[g*8+jj][nb*16+c] = vT[(nb*16+c)*36 + g*8+jj]
  float* op = obuf + (size_t)p * NKC;
#pragma unroll
  for (int nb = 0; nb < 8; ++nb) {
    FU u;
    const ushort* vrow = vT + (nb * 16 + c) * 36 + g * 8;
    u.h[0] = *reinterpret_cast<const bf16x4*>(vrow);
    u.h[1] = *reinterpret_cast<const bf16x4*>(vrow + 4);
    bf16x8 vf = u.v;
#pragma unroll
    for (int i = 0; i < 2; ++i) {
      f32x4 pv = (f32x4){0.f, 0.f, 0.f, 0.f};
      pv = __builtin_amdgcn_mfma_f32_16x16x32_bf16(wa[i], vf, pv, 0, 0, 0);
      if (i == 0) {
#pragma unroll
        for (int q = 0; q < 4; ++q)
          op[(g * 4 + q) * 128 + nb * 16 + c] = pv[q];
      } else if (g < 2) {
#pragma unroll
        for (int q = 0; q < 4; ++q)
          op[(16 + g * 4 + q) * 128 + nb * 16 + c] = pv[q];
      }
    }
  }
}

// ---------------------------------------------------------------------------
// K3: LN stats per (bb,kk) from obuf f32 [row=(bb,t)][kk*128+n]
// ---------------------------------------------------------------------------
__global__ __launch_bounds__(256) void ln_stats_kernel(
    const float* __restrict__ obuf, float* __restrict__ stats)
{
  const int b = blockIdx.x;  // bb*24+kk
  const int bb = b / NHEAD, kk = b % NHEAD;
  const int tid = threadIdx.x;
  float s = 0.f, s2 = 0.f;
  for (int c = tid; c < TDIM * 32; c += 256) {
    int tt = c >> 5, n0 = (c & 31) * 4;
    float4 v = *reinterpret_cast<const float4*>(
        obuf + ((size_t)(bb * TDIM + tt)) * NKC + kk * NDIM + n0);
    s += v.x + v.y + v.z + v.w;
    s2 += v.x * v.x + v.y * v.y + v.z * v.z + v.w * v.w;
  }
  __shared__ float rs[256], rs2[256];
  rs[tid] = s; rs2[tid] = s2;
  __syncthreads();
  for (int off = 128; off > 0; off >>= 1) {
    if (tid < off) { rs[tid] += rs[tid + off]; rs2[tid] += rs2[tid + off]; }
    __syncthreads();
  }
  if (tid == 0) {
    const float inv = 1.f / (NDIM * TDIM);
    float mu = rs[0] * inv;
    float var = rs2[0] * inv - mu * mu;
    stats[b] = mu;
    stats[384 + b] = rsqrtf(var + LN_EPS);
  }
}

// ---------------------------------------------------------------------------
// K4: fused transpose + LN apply: obuf f32 -> out f32 [bb][n][kk][t]
// ---------------------------------------------------------------------------
__global__ __launch_bounds__(256) void transpose_apply_kernel(
    const float* __restrict__ obuf, const float* __restrict__ stats,
    const float* __restrict__ gamma, const float* __restrict__ beta,
    float* __restrict__ out)
{
  __shared__ float tile[32][NDIM + 1];
  const int tid = threadIdx.x;
  const int bb = blockIdx.z, kk = blockIdx.y;
  const int t0 = blockIdx.x * 32;
  const float mu = stats[bb * NHEAD + kk];
  const float rstd = stats[384 + bb * NHEAD + kk];

  for (int c = tid; c < 32 * 32; c += 256) {
    int tl = c >> 5, n0 = (c & 31) * 4;
    if (t0 + tl < TDIM) {
      float4 v = *reinterpret_cast<const float4*>(
          obuf + ((size_t)(bb * TDIM + t0 + tl)) * NKC + kk * NDIM + n0);
      tile[tl][n0] = v.x; tile[tl][n0 + 1] = v.y;
      tile[tl][n0 + 2] = v.z; tile[tl][n0 + 3] = v.w;
    }
  }
  __syncthreads();
  for (int c = tid; c < NDIM * 32; c += 256) {
    int n = c >> 5, tl = c & 31;
    int t = t0 + tl;
    if (t < TDIM) {
      float gmv = gamma[(size_t)n * TDIM + t];
      float btv = beta[(size_t)n * TDIM + t];
      out[(((size_t)bb * NDIM + n) * NHEAD + kk) * TDIM + t] =
          (tile[tl][n] - mu) * rstd * gmv + btv;
    }
  }
}

// ---------------------------------------------------------------------------
extern "C" void kernel_launch(void* const* d_in, const int* in_sizes, int n_in,
                              void* d_out, int out_size, void* d_ws, size_t ws_size,
                              hipStream_t stream) {
  const float* x     = (const float*)d_in[0];
  const float* Wq    = (const float*)d_in[1];
  const float* bq    = (const float*)d_in[2];
  const float* Wk    = (const float*)d_in[3];
  const float* bk    = (const float*)d_in[4];
  const float* Wv    = (const float*)d_in[5];
  const float* bv    = (const float*)d_in[6];
  const float* gamma = (const float*)d_in[7];
  const float* beta  = (const float*)d_in[8];
  float* out = (float*)d_out;

  char* wsb = (char*)d_ws;
  float* stats = (float*)wsb;                       // 1024 floats
  ushort* A = (ushort*)(wsb + 4096);                // [8320][128] bf16
  ushort* B = A + (size_t)MPAD * KPAD;              // [9216][128] bf16
  ushort* qb = B + (size_t)NCOLS * KPAD;            // [8272][3072] bf16 each
  ushort* kb = qb + (size_t)MROWS * NKC;
  ushort* vb = kb + (size_t)MROWS * NKC;
  float* obuf = (float*)(vb + (size_t)MROWS * NKC); // [8272][3072] f32

  convert_x_kernel<<<dim3(9, NBB), 256, 0, stream>>>(x, A);
  convert_w_kernel<<<(NCOLS * 16 + 255) / 256, 256, 0, stream>>>(Wq, Wk, Wv, B, A);
  proj_mfma_kernel<<<dim3(MPAD / 128, NCOLS / 128), 256, 0, stream>>>(
      A, B, bq, bk, bv, qb, kb, vb);
  attn_mfma_kernel<<<MROWS / 4, 256, 0, stream>>>(qb, kb, vb, obuf);
  ln_stats_kernel<<<NBB * NHEAD, 256, 0, stream>>>(obuf, stats);
  transpose_apply_kernel<<<dim3((TDIM + 31) / 32, NHEAD, NBB), 256, 0, stream>>>(
      obuf, stats, gamma, beta, out);
}

// Round 6
// 204.233 us; speedup vs baseline: 4.9427x; 1.0631x over previous
//
#include <hip/hip_runtime.h>
#include <hip/hip_bf16.h>
#include <cstdint>

#define TDIM 517
#define FEATD 120
#define NBB 16
#define NHEAD 24
#define NDIM 128
#define NKC 3072            // NHEAD*NDIM
#define MROWS (NBB * TDIM)  // 8272
#define MPAD 8320           // 65 * 128
#define NCOLS (3 * NKC)     // 9216
#define KPAD 128
#define LN_EPS 1e-5f

typedef short bf16x8 __attribute__((ext_vector_type(8)));
typedef short bf16x4 __attribute__((ext_vector_type(4)));
typedef float f32x4 __attribute__((ext_vector_type(4)));

static __device__ __forceinline__ float bf2f(ushort u) {
  union { uint i; float f; } v; v.i = ((uint)u) << 16; return v.f;
}
static __device__ __forceinline__ ushort f2bf(float f) {
  __hip_bfloat16 h = __float2bfloat16(f);   // RNE
  return *reinterpret_cast<ushort*>(&h);
}

// ---------------------------------------------------------------------------
// K0a: x [16][120][517] f32  ->  A [row=(bb*517+tt)][kpad=128] bf16 (f>=120 zero)
// ---------------------------------------------------------------------------
__global__ __launch_bounds__(256) void convert_x_kernel(
    const float* __restrict__ x, ushort* __restrict__ A)
{
  __shared__ float tile[FEATD][65];
  const int tid = threadIdx.x;
  const int bb = blockIdx.y;
  const int t0 = blockIdx.x * 64;
  const int nt = min(64, TDIM - t0);
  for (int idx = tid; idx < FEATD * 64; idx += 256) {
    int f = idx >> 6, tl = idx & 63;
    if (tl < nt) tile[f][tl] = x[((size_t)bb * FEATD + f) * TDIM + t0 + tl];
  }
  __syncthreads();
  for (int c = tid; c < 64 * 16; c += 256) {
    int tl = c >> 4, c8 = c & 15;
    if (tl >= nt) continue;
    ushort u[8];
    if (c8 < 15) {
#pragma unroll
      for (int j = 0; j < 8; ++j) u[j] = f2bf(tile[c8 * 8 + j][tl]);
    } else {
#pragma unroll
      for (int j = 0; j < 8; ++j) u[j] = 0;
    }
    size_t row = (size_t)bb * TDIM + t0 + tl;
    *reinterpret_cast<uint4*>(A + row * KPAD + c8 * 8) = *reinterpret_cast<const uint4*>(u);
  }
}

// ---------------------------------------------------------------------------
// K0b: W{q,k,v} [3072][120] f32 -> B [9216][128] bf16; also zero A tail rows
// ---------------------------------------------------------------------------
__global__ __launch_bounds__(256) void convert_w_kernel(
    const float* __restrict__ Wq, const float* __restrict__ Wk, const float* __restrict__ Wv,
    ushort* __restrict__ B, ushort* __restrict__ A)
{
  const int c = blockIdx.x * 256 + threadIdx.x;
  if (c < NCOLS * 16) {
    int col = c >> 4, c8 = c & 15;
    ushort u[8];
    if (c8 < 15) {
      const float* W = (col < NKC)     ? (Wq + (size_t)col * FEATD)
                     : (col < 2 * NKC) ? (Wk + (size_t)(col - NKC) * FEATD)
                                       : (Wv + (size_t)(col - 2 * NKC) * FEATD);
#pragma unroll
      for (int j = 0; j < 8; ++j) u[j] = f2bf(W[c8 * 8 + j]);
    } else {
#pragma unroll
      for (int j = 0; j < 8; ++j) u[j] = 0;
    }
    *reinterpret_cast<uint4*>(B + (size_t)col * KPAD + c8 * 8) = *reinterpret_cast<const uint4*>(u);
  }
  if (c < (MPAD - MROWS) * 16) {
    uint4 z = {0, 0, 0, 0};
    *reinterpret_cast<uint4*>(A + (size_t)(MROWS + (c >> 4)) * KPAD + (c & 15) * 8) = z;
  }
}

// ---------------------------------------------------------------------------
// K1: MFMA projection GEMM (unchanged from R2)
// ---------------------------------------------------------------------------
__global__ __launch_bounds__(256) void proj_mfma_kernel(
    const ushort* __restrict__ A, const ushort* __restrict__ B,
    const float* __restrict__ bq, const float* __restrict__ bk, const float* __restrict__ bv,
    ushort* __restrict__ qb, ushort* __restrict__ kb, ushort* __restrict__ vb)
{
  __shared__ __align__(16) ushort sA[128 * KPAD];
  __shared__ __align__(16) ushort sB[128 * KPAD];
  __shared__ float sBias[128];
  const int tid  = threadIdx.x;
  const int lane = tid & 63;
  const int wave = tid >> 6;
  const int wm0  = (wave >> 1) * 64;
  const int wn0  = (wave & 1) * 64;
  const int m0   = blockIdx.x * 128;
  const int n0   = blockIdx.y * 128;
  const int mat  = blockIdx.y / 24;
  const int nloc0 = n0 - mat * NKC;
  const float* bias = (mat == 0) ? bq : (mat == 1) ? bk : bv;
  ushort* outb      = (mat == 0) ? qb : (mat == 1) ? kb : vb;

  if (tid < 128) sBias[tid] = bias[nloc0 + tid];

#pragma unroll
  for (int i = 0; i < 8; ++i) {
    int c = tid + i * 256;
    int row = c >> 4, c8 = c & 15;
    uint4 va = *reinterpret_cast<const uint4*>(A + (size_t)(m0 + row) * KPAD + c8 * 8);
    uint4 vb4 = *reinterpret_cast<const uint4*>(B + (size_t)(n0 + row) * KPAD + c8 * 8);
    *reinterpret_cast<uint4*>(&sA[row * KPAD + ((c8 ^ (row & 7)) << 3)]) = va;
    *reinterpret_cast<uint4*>(&sB[row * KPAD + ((c8 ^ (row & 7)) << 3)]) = vb4;
  }
  __syncthreads();

  f32x4 acc[4][4];
#pragma unroll
  for (int i = 0; i < 4; ++i)
#pragma unroll
    for (int j = 0; j < 4; ++j) acc[i][j] = (f32x4){0.f, 0.f, 0.f, 0.f};

  const int rl = lane & 15;
  const int kg = lane >> 4;
#pragma unroll
  for (int s = 0; s < 4; ++s) {
    bf16x8 af[4], bfr[4];
    const int c8 = s * 4 + kg;
#pragma unroll
    for (int i = 0; i < 4; ++i) {
      int row = wm0 + i * 16 + rl;
      af[i] = *reinterpret_cast<const bf16x8*>(&sA[row * KPAD + ((c8 ^ (row & 7)) << 3)]);
      int rowb = wn0 + i * 16 + rl;
      bfr[i] = *reinterpret_cast<const bf16x8*>(&sB[rowb * KPAD + ((c8 ^ (rowb & 7)) << 3)]);
    }
#pragma unroll
    for (int i = 0; i < 4; ++i)
#pragma unroll
      for (int j = 0; j < 4; ++j)
        acc[i][j] = __builtin_amdgcn_mfma_f32_16x16x32_bf16(af[i], bfr[j], acc[i][j], 0, 0, 0);
  }

  __syncthreads();
  ushort* sC = sA;
#pragma unroll
  for (int i = 0; i < 4; ++i)
#pragma unroll
    for (int j = 0; j < 4; ++j) {
      int col = wn0 + j * 16 + rl;
      float bsv = sBias[col];
#pragma unroll
      for (int r = 0; r < 4; ++r) {
        int row = wm0 + i * 16 + kg * 4 + r;
        sC[row * 128 + col] = f2bf(acc[i][j][r] + bsv);
      }
    }
  __syncthreads();
#pragma unroll
  for (int i = 0; i < 8; ++i) {
    int c = tid + i * 256;
    int row = c >> 4, c8 = c & 15;
    int grow = m0 + row;
    if (grow < MROWS)
      *reinterpret_cast<uint4*>(outb + (size_t)grow * NKC + nloc0 + c8 * 8) =
          *reinterpret_cast<const uint4*>(&sC[row * 128 + c8 * 8]);
  }
}

// ---------------------------------------------------------------------------
// K2: MFMA attention + fused LN partial stats.
// 1 wave per (bb,t); 4 waves/block; per-wave LDS slices.
// Per-(bb,kk) sum/sumsq partials: lane-accumulate -> shfl-reduce over the
// 16-lane c-group -> lane c==0 writes part[p][2*kk{,+1}]. Deterministic.
// ---------------------------------------------------------------------------
#define WAVE_LDS 5760
__global__ __launch_bounds__(256) void attn_mfma_kernel(
    const ushort* __restrict__ qb, const ushort* __restrict__ kb,
    const ushort* __restrict__ vb, float* __restrict__ obuf,
    float* __restrict__ part)
{
  __shared__ __align__(16) ushort lds[4 * WAVE_LDS];
  const int tid  = threadIdx.x;
  const int wave = tid >> 6;
  const int lane = tid & 63;
  const int c = lane & 15;
  const int g = lane >> 4;
  const int p = blockIdx.x * 4 + wave;
  ushort* vT = lds + wave * WAVE_LDS;   // [n][36]: vT[n*36+m] = V[m][n]
  ushort* wL = vT + 4608;               // [row][36]: wei
  const ushort* qp = qb + (size_t)p * NKC;
  const ushort* kp = kb + (size_t)p * NKC;
  const ushort* vp = vb + (size_t)p * NKC;

  // ---- issue V global loads early (T14: hide under QK^T+softmax) ----
  uint4 vload[6];
#pragma unroll
  for (int it = 0; it < 6; ++it) {
    int idx = it * 64 + lane;
    int m = idx >> 4, n0 = (idx & 15) * 8;
    vload[it] = *reinterpret_cast<const uint4*>(vp + m * 128 + n0);
  }

  // ---- QK^T: S[kk][m], kk rows on A(Q), m cols on B(K) ----
  f32x4 sc[2][2];
#pragma unroll
  for (int i = 0; i < 2; ++i)
#pragma unroll
    for (int j = 0; j < 2; ++j) sc[i][j] = (f32x4){0.f, 0.f, 0.f, 0.f};

#pragma unroll
  for (int s = 0; s < 4; ++s) {
    bf16x8 aq[2], bk2[2];
#pragma unroll
    for (int i = 0; i < 2; ++i)
      aq[i] = *reinterpret_cast<const bf16x8*>(qp + (i * 16 + c) * 128 + s * 32 + g * 8);
#pragma unroll
    for (int j = 0; j < 2; ++j)
      bk2[j] = *reinterpret_cast<const bf16x8*>(kp + (j * 16 + c) * 128 + s * 32 + g * 8);
#pragma unroll
    for (int i = 0; i < 2; ++i)
#pragma unroll
      for (int j = 0; j < 2; ++j)
        sc[i][j] = __builtin_amdgcn_mfma_f32_16x16x32_bf16(aq[i], bk2[j], sc[i][j], 0, 0, 0);
  }

  // ---- softmax over m per row; lane holds S[i*16+g*4+r][j*16+c] ----
#pragma unroll
  for (int i = 0; i < 2; ++i) {
#pragma unroll
    for (int r = 0; r < 4; ++r) {
      float s0 = sc[i][0][r];
      float s1 = (c < 8) ? sc[i][1][r] : -1e30f;
      float mx = fmaxf(s0, s1);
#pragma unroll
      for (int d = 1; d < 16; d <<= 1) mx = fmaxf(mx, __shfl_xor(mx, d));
      float e0 = __expf(s0 - mx);
      float e1 = (c < 8) ? __expf(s1 - mx) : 0.f;
      float sum = e0 + e1;
#pragma unroll
      for (int d = 1; d < 16; d <<= 1) sum += __shfl_xor(sum, d);
      float inv = 1.f / sum;
      int row = i * 16 + g * 4 + r;
      wL[row * 36 + c]      = f2bf(e0 * inv);
      wL[row * 36 + 16 + c] = f2bf(e1 * inv);
    }
  }

  // ---- stage V transposed: vT[n*36 + m] = V[m][n] (scalar scatter) ----
#pragma unroll
  for (int it = 0; it < 6; ++it) {
    int idx = it * 64 + lane;
    int m = idx >> 4, n0 = (idx & 15) * 8;
    uint w0 = vload[it].x, w1 = vload[it].y, w2 = vload[it].z, w3 = vload[it].w;
    vT[(n0 + 0) * 36 + m] = (ushort)(w0 & 0xffff);
    vT[(n0 + 1) * 36 + m] = (ushort)(w0 >> 16);
    vT[(n0 + 2) * 36 + m] = (ushort)(w1 & 0xffff);
    vT[(n0 + 3) * 36 + m] = (ushort)(w1 >> 16);
    vT[(n0 + 4) * 36 + m] = (ushort)(w2 & 0xffff);
    vT[(n0 + 5) * 36 + m] = (ushort)(w2 >> 16);
    vT[(n0 + 6) * 36 + m] = (ushort)(w3 & 0xffff);
    vT[(n0 + 7) * 36 + m] = (ushort)(w3 >> 16);
  }
  // zero pad m=24..31 for all n (ALL halfwords — R3 lesson)
#pragma unroll
  for (int h = 0; h < 16; ++h) {
    int idx = h * 64 + lane;        // 0..1023
    int n = idx >> 3, mm = 24 + (idx & 7);
    vT[n * 36 + mm] = 0;
  }

  // ---- PV A-frags (wei): row=i*16+c, k-chunk g*8 ----
  union FU { bf16x4 h[2]; bf16x8 v; };
  bf16x8 wa[2];
#pragma unroll
  for (int i = 0; i < 2; ++i) {
    FU u;
    u.h[0] = *reinterpret_cast<const bf16x4*>(wL + (i * 16 + c) * 36 + g * 8);
    u.h[1] = *reinterpret_cast<const bf16x4*>(wL + (i * 16 + c) * 36 + g * 8 + 4);
    wa[i] = u.v;
  }

  // ---- PV + O-write + LN partial accumulation ----
  float ls0[4] = {0.f, 0.f, 0.f, 0.f}, ls20[4] = {0.f, 0.f, 0.f, 0.f};
  float ls1[4] = {0.f, 0.f, 0.f, 0.f}, ls21[4] = {0.f, 0.f, 0.f, 0.f};
  float* op = obuf + (size_t)p * NKC;
#pragma unroll
  for (int nb = 0; nb < 8; ++nb) {
    FU u;
    const ushort* vrow = vT + (nb * 16 + c) * 36 + g * 8;
    u.h[0] = *reinterpret_cast<const bf16x4*>(vrow);
    u.h[1] = *reinterpret_cast<const bf16x4*>(vrow + 4);
    bf16x8 vf = u.v;
#pragma unroll
    for (int i = 0; i < 2; ++i) {
      f32x4 pv = (f32x4){0.f, 0.f, 0.f, 0.f};
      pv = __builtin_amdgcn_mfma_f32_16x16x32_bf16(wa[i], vf, pv, 0, 0, 0);
      if (i == 0) {
#pragma unroll
        for (int q = 0; q < 4; ++q) {
          op[(g * 4 + q) * 128 + nb * 16 + c] = pv[q];
          ls0[q] += pv[q];
          ls20[q] += pv[q] * pv[q];
        }
      } else if (g < 2) {
#pragma unroll
        for (int q = 0; q < 4; ++q) {
          op[(16 + g * 4 + q) * 128 + nb * 16 + c] = pv[q];
          ls1[q] += pv[q];
          ls21[q] += pv[q] * pv[q];
        }
      }
    }
  }

  // reduce over the 16-lane c-group (xor masks < 16 stay within group)
#pragma unroll
  for (int q = 0; q < 4; ++q) {
#pragma unroll
    for (int d = 1; d < 16; d <<= 1) {
      ls0[q]  += __shfl_xor(ls0[q], d);
      ls20[q] += __shfl_xor(ls20[q], d);
      ls1[q]  += __shfl_xor(ls1[q], d);
      ls21[q] += __shfl_xor(ls21[q], d);
    }
  }
  if (c == 0) {
    float* pr = part + (size_t)p * 48;
#pragma unroll
    for (int q = 0; q < 4; ++q) {
      int kk = g * 4 + q;
      pr[2 * kk]     = ls0[q];
      pr[2 * kk + 1] = ls20[q];
    }
    if (g < 2) {
#pragma unroll
      for (int q = 0; q < 4; ++q) {
        int kk = 16 + g * 4 + q;
        pr[2 * kk]     = ls1[q];
        pr[2 * kk + 1] = ls21[q];
      }
    }
  }
}

// ---------------------------------------------------------------------------
// K3: reduce per-(bb,t) partials -> stats (mu, rstd) per (bb,kk). ~1.6 MB read.
// ---------------------------------------------------------------------------
__global__ __launch_bounds__(256) void ln_part_reduce_kernel(
    const float* __restrict__ part, float* __restrict__ stats)
{
  const int b = blockIdx.x;  // bb*24+kk
  const int bb = b / NHEAD, kk = b % NHEAD;
  const int tid = threadIdx.x;
  float s = 0.f, s2 = 0.f;
  for (int tt = tid; tt < TDIM; tt += 256) {
    const float* pr = part + ((size_t)(bb * TDIM + tt)) * 48 + 2 * kk;
    s += pr[0];
    s2 += pr[1];
  }
  __shared__ float rs[256], rs2[256];
  rs[tid] = s; rs2[tid] = s2;
  __syncthreads();
  for (int off = 128; off > 0; off >>= 1) {
    if (tid < off) { rs[tid] += rs[tid + off]; rs2[tid] += rs2[tid + off]; }
    __syncthreads();
  }
  if (tid == 0) {
    const float inv = 1.f / (NDIM * TDIM);
    float mu = rs[0] * inv;
    float var = rs2[0] * inv - mu * mu;
    stats[b] = mu;
    stats[384 + b] = rsqrtf(var + LN_EPS);
  }
}

// ---------------------------------------------------------------------------
// K4: fused transpose + LN apply: obuf f32 -> out f32 [bb][n][kk][t]
// Vectorized: each thread writes 4 consecutive t (f32x4 via memcpy; rows are
// only 4B-aligned since TDIM=517 is odd -> unaligned dwordx4, HW-supported).
// ---------------------------------------------------------------------------
__global__ __launch_bounds__(256) void transpose_apply_kernel(
    const float* __restrict__ obuf, const float* __restrict__ stats,
    const float* __restrict__ gamma, const float* __restrict__ beta,
    float* __restrict__ out)
{
  __shared__ float tile[32][NDIM + 1];
  const int tid = threadIdx.x;
  const int bb = blockIdx.z, kk = blockIdx.y;
  const int t0 = blockIdx.x * 32;
  const float mu = stats[bb * NHEAD + kk];
  const float rstd = stats[384 + bb * NHEAD + kk];

  for (int c = tid; c < 32 * 32; c += 256) {
    int tl = c >> 5, n0 = (c & 31) * 4;
    if (t0 + tl < TDIM) {
      float4 v = *reinterpret_cast<const float4*>(
          obuf + ((size_t)(bb * TDIM + t0 + tl)) * NKC + kk * NDIM + n0);
      tile[tl][n0] = v.x; tile[tl][n0 + 1] = v.y;
      tile[tl][n0 + 2] = v.z; tile[tl][n0 + 3] = v.w;
    }
  }
  __syncthreads();

  if (t0 + 32 <= TDIM) {
    // full tile: vector path. thread -> (n = c>>3, tq = c&7), 4 t's each.
    for (int c = tid; c < NDIM * 8; c += 256) {
      int n = c >> 3, tq = c & 7;
      int t = t0 + tq * 4;
      const size_t gbase = (size_t)n * TDIM + t;
      float vals[4];
#pragma unroll
      for (int j = 0; j < 4; ++j)
        vals[j] = (tile[tq * 4 + j][n] - mu) * rstd * gamma[gbase + j] + beta[gbase + j];
      float* dst = out + (((size_t)bb * NDIM + n) * NHEAD + kk) * TDIM + t;
      __builtin_memcpy(dst, vals, 16);
    }
  } else {
    // ragged tail (t0=512, nt=5): scalar path
    for (int c = tid; c < NDIM * 32; c += 256) {
      int n = c >> 5, tl = c & 31;
      int t = t0 + tl;
      if (t < TDIM) {
        float gmv = gamma[(size_t)n * TDIM + t];
        float btv = beta[(size_t)n * TDIM + t];
        out[(((size_t)bb * NDIM + n) * NHEAD + kk) * TDIM + t] =
            (tile[tl][n] - mu) * rstd * gmv + btv;
      }
    }
  }
}

// ---------------------------------------------------------------------------
extern "C" void kernel_launch(void* const* d_in, const int* in_sizes, int n_in,
                              void* d_out, int out_size, void* d_ws, size_t ws_size,
                              hipStream_t stream) {
  const float* x     = (const float*)d_in[0];
  const float* Wq    = (const float*)d_in[1];
  const float* bq    = (const float*)d_in[2];
  const float* Wk    = (const float*)d_in[3];
  const float* bk    = (const float*)d_in[4];
  const float* Wv    = (const float*)d_in[5];
  const float* bv    = (const float*)d_in[6];
  const float* gamma = (const float*)d_in[7];
  const float* beta  = (const float*)d_in[8];
  float* out = (float*)d_out;

  char* wsb = (char*)d_ws;
  float* stats = (float*)wsb;                       // 1024 floats
  ushort* A = (ushort*)(wsb + 4096);                // [8320][128] bf16
  ushort* B = A + (size_t)MPAD * KPAD;              // [9216][128] bf16
  ushort* qb = B + (size_t)NCOLS * KPAD;            // [8272][3072] bf16 each
  ushort* kb = qb + (size_t)MROWS * NKC;
  ushort* vb = kb + (size_t)MROWS * NKC;
  float* obuf = (float*)(vb + (size_t)MROWS * NKC); // [8272][3072] f32
  float* part = obuf + (size_t)MROWS * NKC;         // [8272][48] f32

  convert_x_kernel<<<dim3(9, NBB), 256, 0, stream>>>(x, A);
  convert_w_kernel<<<(NCOLS * 16 + 255) / 256, 256, 0, stream>>>(Wq, Wk, Wv, B, A);
  proj_mfma_kernel<<<dim3(MPAD / 128, NCOLS / 128), 256, 0, stream>>>(
      A, B, bq, bk, bv, qb, kb, vb);
  attn_mfma_kernel<<<MROWS / 4, 256, 0, stream>>>(qb, kb, vb, obuf, part);
  ln_part_reduce_kernel<<<NBB * NHEAD, 256, 0, stream>>>(part, stats);
  transpose_apply_kernel<<<dim3((TDIM + 31) / 32, NHEAD, NBB), 256, 0, stream>>>(
      obuf, stats, gamma, beta, out);
}